// Round 28
// baseline (34.835 us; speedup 1.0000x reference)
//
#include <hip/hip_runtime.h>
#include <hip/hip_fp16.h>

// out[m][n] = fp16( fp16( (sum_k x[m][k]*w6[n][k]) * scale[n] ) + bias[n] ), stored fp32
// v26 = v23 (tile 128x64, BK=32, 4 waves 64x32, linear fp16 LDS, 4 blocks/CU, SPL=8,
// fp16 partials, v18 finalize) + ONE change: 2-deep register prefetch with counted
// vmcnt(6). v23 waited vmcnt(0) on loads issued the same phase (~300cy exposed/phase);
// now the wait leaves the NEXT tile's 6 loads in flight -> full-phase latency cover.

typedef __attribute__((ext_vector_type(8))) _Float16 half8;
typedef __attribute__((ext_vector_type(4))) _Float16 half4;
typedef __attribute__((ext_vector_type(2))) __fp16 fp16x2;   // cvt_pkrtz return type
typedef __attribute__((ext_vector_type(4))) float f32x4;

constexpr int K = 4096, N = 4096, M = 256;
constexpr int BM = 128, BN = 64, BK = 32;
constexpr int SPL = 8;
constexpr int KSPL = K / SPL;     // 512
constexpr int NT = KSPL / BK;     // 16 phases

__device__ __forceinline__ half4 cvt4(float4 f) {   // exact: fp16-exact data
    fp16x2 p0 = __builtin_amdgcn_cvt_pkrtz(f.x, f.y);
    fp16x2 p1 = __builtin_amdgcn_cvt_pkrtz(f.z, f.w);
    half4 h;
    h[0]=(_Float16)p0[0]; h[1]=(_Float16)p0[1];
    h[2]=(_Float16)p1[0]; h[3]=(_Float16)p1[1];
    return h;
}

__global__ __launch_bounds__(256, 4)
void gemm(const float* __restrict__ X,
          const float* __restrict__ W,
          _Float16* __restrict__ P)     // [SPL][M][N] fp16 partials
{
    __shared__ __align__(16) _Float16 LA[2][BM * BK];   // 2 x 8 KB fp16 (linear, v23)
    __shared__ __align__(16) _Float16 LB[2][BN * BK];   // 2 x 4 KB fp16

    const int tid = (int)threadIdx.x;
    const int l   = tid & 63;
    const int wv  = tid >> 6;           // 4 waves: 2(M) x 2(N), wave tile 64x32
    const int lc  = l & 15;
    const int lr  = l >> 4;
    const int wm  = (wv & 1) * 64;
    const int wn  = (wv >> 1) * 32;

    // grid 1024 = xcd(8) x [mb(2) x sp(8) x nbl(8)]; per XCD 512 W rows HBM-once.
    const int bid = (int)blockIdx.x;
    const int xcd = bid & 7;
    const int i   = bid >> 3;           // 0..127
    const int mb  = i & 1;
    const int sp  = (i >> 1) & 7;
    const int nbl = i >> 4;             // 0..7
    const int bm  = mb * BM;
    const int bn  = (xcd * 8 + nbl) * BN;
    const int kb  = sp * KSPL;

    // ---- staging maps (fp32 global -> regs; coalesced 1KB/inst) ----
    const int arow = wv * 32 + (l >> 3);             // A: 4 insts (+8 rows)
    const int wrow = wv * 16 + (l >> 3);             // W: 2 insts (+8 rows)
    const int scol = (l & 7) * 4;
    const float* ax0 = X + (size_t)(bm + arow)      * K + kb + scol;
    const float* ax1 = X + (size_t)(bm + arow + 8)  * K + kb + scol;
    const float* ax2 = X + (size_t)(bm + arow + 16) * K + kb + scol;
    const float* ax3 = X + (size_t)(bm + arow + 24) * K + kb + scol;
    const float* wx0 = W + (size_t)(bn + wrow)      * K + kb + scol;
    const float* wx1 = W + (size_t)(bn + wrow + 8)  * K + kb + scol;
    // LDS half-index write bases (linear rows, v23)
    const int awr = arow * BK + (l & 7) * 4;
    const int wwr = wrow * BK + (l & 7) * 4;

    // TWO named register slot sets (rule 20): 2-deep pipeline (the one change vs v23)
    float4 sa0, sa1, sa2, sa3, sw0, sw1;     // slot 0 (even tiles)
    float4 ta0, ta1, ta2, ta3, tw0, tw1;     // slot 1 (odd tiles)

#define GLOAD0(t) do { const size_t o = (size_t)(t) * BK;               \
        sa0 = *(const float4*)(ax0 + o); sa1 = *(const float4*)(ax1 + o); \
        sa2 = *(const float4*)(ax2 + o); sa3 = *(const float4*)(ax3 + o); \
        sw0 = *(const float4*)(wx0 + o); sw1 = *(const float4*)(wx1 + o); } while (0)
#define GLOAD1(t) do { const size_t o = (size_t)(t) * BK;               \
        ta0 = *(const float4*)(ax0 + o); ta1 = *(const float4*)(ax1 + o); \
        ta2 = *(const float4*)(ax2 + o); ta3 = *(const float4*)(ax3 + o); \
        tw0 = *(const float4*)(wx0 + o); tw1 = *(const float4*)(wx1 + o); } while (0)
#define CVTW0(bf) do {                                                  \
        *(half4*)(&LA[bf][awr])          = cvt4(sa0);                   \
        *(half4*)(&LA[bf][awr + 8*BK])   = cvt4(sa1);                   \
        *(half4*)(&LA[bf][awr + 16*BK])  = cvt4(sa2);                   \
        *(half4*)(&LA[bf][awr + 24*BK])  = cvt4(sa3);                   \
        *(half4*)(&LB[bf][wwr])          = cvt4(sw0);                   \
        *(half4*)(&LB[bf][wwr + 8*BK])   = cvt4(sw1); } while (0)
#define CVTW1(bf) do {                                                  \
        *(half4*)(&LA[bf][awr])          = cvt4(ta0);                   \
        *(half4*)(&LA[bf][awr + 8*BK])   = cvt4(ta1);                   \
        *(half4*)(&LA[bf][awr + 16*BK])  = cvt4(ta2);                   \
        *(half4*)(&LA[bf][awr + 24*BK])  = cvt4(ta3);                   \
        *(half4*)(&LB[bf][wwr])          = cvt4(tw0);                   \
        *(half4*)(&LB[bf][wwr + 8*BK])   = cvt4(tw1); } while (0)

    f32x4 acc[4][2];
    #pragma unroll
    for (int a = 0; a < 4; ++a)
        #pragma unroll
        for (int b = 0; b < 2; ++b)
            acc[a][b] = (f32x4){0.f, 0.f, 0.f, 0.f};

    // frags: direct half8 at [row][lr*8] (16B contiguous, v23 layout)
#define COMPUTE(bf) do {                                                \
        half8 af[4], wf[2];                                             \
        _Pragma("unroll")                                               \
        for (int ar = 0; ar < 4; ++ar)                                  \
            af[ar] = *(const half8*)(&LA[bf][(wm + ar * 16 + lc) * BK + lr * 8]); \
        _Pragma("unroll")                                               \
        for (int br = 0; br < 2; ++br)                                  \
            wf[br] = *(const half8*)(&LB[bf][(wn + br * 16 + lc) * BK + lr * 8]); \
        _Pragma("unroll")                                               \
        for (int ar = 0; ar < 4; ++ar)                                  \
            _Pragma("unroll")                                           \
            for (int br = 0; br < 2; ++br)                              \
                acc[ar][br] = __builtin_amdgcn_mfma_f32_16x16x32_f16(   \
                    af[ar], wf[br], acc[ar][br], 0, 0, 0); } while (0)

    // prologue: tiles 0,1 in flight; cvt tile0 -> buf0 (tile1 stays outstanding)
    GLOAD0(0);
    GLOAD1(1);
    asm volatile("s_waitcnt vmcnt(6)" ::: "memory");
    CVTW0(0);
    asm volatile("s_waitcnt lgkmcnt(0)" ::: "memory");
    __builtin_amdgcn_s_barrier();

    for (int t2 = 0; t2 < NT; t2 += 2) {
        // ---- even phase: compute buf0 (tile t2) ----
        if (t2 + 2 < NT) GLOAD0(t2 + 2);           // refill slot0 (freed by prev CVTW0)
        __builtin_amdgcn_sched_barrier(0);
        COMPUTE(0);
        if (t2 + 2 < NT) { asm volatile("s_waitcnt vmcnt(6)" ::: "memory"); }
        else             { asm volatile("s_waitcnt vmcnt(0)" ::: "memory"); }
        __builtin_amdgcn_sched_barrier(0);
        CVTW1(1);                                   // tile t2+1 -> buf1
        asm volatile("s_waitcnt lgkmcnt(0)" ::: "memory");
        __builtin_amdgcn_s_barrier();
        // ---- odd phase: compute buf1 (tile t2+1) ----
        if (t2 + 3 < NT) GLOAD1(t2 + 3);           // refill slot1
        __builtin_amdgcn_sched_barrier(0);
        COMPUTE(1);
        if (t2 + 2 < NT) {
            if (t2 + 3 < NT) { asm volatile("s_waitcnt vmcnt(6)" ::: "memory"); }
            else             { asm volatile("s_waitcnt vmcnt(0)" ::: "memory"); }
            __builtin_amdgcn_sched_barrier(0);
            CVTW0(0);                               // tile t2+2 -> buf0
            asm volatile("s_waitcnt lgkmcnt(0)" ::: "memory");
            __builtin_amdgcn_s_barrier();
        }
    }
#undef GLOAD0
#undef GLOAD1
#undef CVTW0
#undef CVTW1
#undef COMPUTE

    // fp16 partial stores. C/D: col = lane&15, row = (lane>>4)*4 + reg [m89/m91]
    _Float16* Pb = P + (size_t)sp * M * N;
    const int orow = bm + wm + lr * 4;
    const int ocol = bn + wn + lc;
    #pragma unroll
    for (int ar = 0; ar < 4; ++ar)
        #pragma unroll
        for (int br = 0; br < 2; ++br)
            #pragma unroll
            for (int r = 0; r < 4; ++r)
                Pb[(size_t)(orow + ar * 16 + r) * N + ocol + br * 16]
                    = (_Float16)acc[ar][br][r];
}

// O = fp32( fp16( fp16( (sum of SPL fp16 partials) * scale[n] ) + bias[n] ) )  (v18)
__global__ __launch_bounds__(256)
void finalize(const _Float16* __restrict__ P,
              const float* __restrict__ S,
              const float* __restrict__ Bi,
              float* __restrict__ O)
{
    const size_t i = ((size_t)blockIdx.x * 256 + threadIdx.x) * 8;
    const int n = (int)(i & (N - 1));
    float acc[8] = {0.f, 0.f, 0.f, 0.f, 0.f, 0.f, 0.f, 0.f};
    #pragma unroll
    for (int s = 0; s < SPL; ++s) {
        half8 u = *(const half8*)(P + (size_t)s * M * N + i);
        #pragma unroll
        for (int e = 0; e < 8; ++e) acc[e] += (float)u[e];
    }
    float4 sc0 = *(const float4*)(S + n);
    float4 sc1 = *(const float4*)(S + n + 4);
    float4 bb0 = *(const float4*)(Bi + n);
    float4 bb1 = *(const float4*)(Bi + n + 4);
    float sc[8] = {sc0.x, sc0.y, sc0.z, sc0.w, sc1.x, sc1.y, sc1.z, sc1.w};
    float bb[8] = {bb0.x, bb0.y, bb0.z, bb0.w, bb1.x, bb1.y, bb1.z, bb1.w};
    float out[8];
    #pragma unroll
    for (int e = 0; e < 8; ++e)
        out[e] = (float)(_Float16)((float)(_Float16)(acc[e] * sc[e]) + bb[e]);
    *(float4*)(O + i)     = (float4){out[0], out[1], out[2], out[3]};
    *(float4*)(O + i + 4) = (float4){out[4], out[5], out[6], out[7]};
}

// correctness fallback if d_ws is too small
__global__ __launch_bounds__(256)
void fp6lin_small(const float* __restrict__ X, const float* __restrict__ W,
                  const float* __restrict__ S, const float* __restrict__ Bi,
                  float* __restrict__ O)
{
    const int n = (int)blockIdx.x;
    const int m = (int)threadIdx.x;
    float s = 0.f;
    for (int k = 0; k < K; ++k)
        s += (float)(_Float16)X[(size_t)m * K + k] * (float)(_Float16)W[(size_t)n * K + k];
    O[(size_t)m * N + n] = (float)(_Float16)((float)(_Float16)(s * S[n]) + Bi[n]);
}

extern "C" void kernel_launch(void* const* d_in, const int* in_sizes, int n_in,
                              void* d_out, int out_size, void* d_ws, size_t ws_size,
                              hipStream_t stream) {
    const float* x  = (const float*)d_in[0];
    const float* w  = (const float*)d_in[1];
    const float* s  = (const float*)d_in[2];
    const float* bi = (const float*)d_in[3];
    float* o = (float*)d_out;

    const size_t pbytes = (size_t)SPL * M * N * 2;   // 16 MB fp16 partials
    _Float16* P = (_Float16*)d_ws;

    if (ws_size >= pbytes) {
        gemm<<<dim3(1024), dim3(256), 0, stream>>>(x, w, P);
        finalize<<<dim3(M * N / 8 / 256), dim3(256), 0, stream>>>(P, s, bi, o);
    } else {
        fp6lin_small<<<dim3(N), dim3(M), 0, stream>>>(x, w, s, bi, o);
    }
}

// Round 29
// 30.943 us; speedup vs baseline: 1.1258x; 1.1258x over previous
//
#include <hip/hip_runtime.h>
#include <hip/hip_fp16.h>

// out[m][n] = fp16( fp16( (sum_k x[m][k]*w6[n][k]) * scale[n] ) + bias[n] ), stored fp32
// v27 = v23 gemm VERBATIM (tile 128x64, BK=32, 4 waves 64x32, linear fp16 LDS,
// reg-staged cvt, same-phase vmcnt(0), ONE raw barrier/phase, 4 blocks/CU, SPL=8,
// fp16 partials) + ONE change vs the 30.5us best: XCD-swizzled finalize (partials
// for cols [xcd*512..+512) were written by that XCD's blocks -> read them L2-local).

typedef __attribute__((ext_vector_type(8))) _Float16 half8;
typedef __attribute__((ext_vector_type(4))) _Float16 half4;
typedef __attribute__((ext_vector_type(2))) __fp16 fp16x2;   // cvt_pkrtz return type
typedef __attribute__((ext_vector_type(4))) float f32x4;

constexpr int K = 4096, N = 4096, M = 256;
constexpr int BM = 128, BN = 64, BK = 32;
constexpr int SPL = 8;
constexpr int KSPL = K / SPL;     // 512
constexpr int NT = KSPL / BK;     // 16 phases

__device__ __forceinline__ half4 cvt4(float4 f) {   // exact: fp16-exact data
    fp16x2 p0 = __builtin_amdgcn_cvt_pkrtz(f.x, f.y);
    fp16x2 p1 = __builtin_amdgcn_cvt_pkrtz(f.z, f.w);
    half4 h;
    h[0]=(_Float16)p0[0]; h[1]=(_Float16)p0[1];
    h[2]=(_Float16)p1[0]; h[3]=(_Float16)p1[1];
    return h;
}

__global__ __launch_bounds__(256, 4)
void gemm(const float* __restrict__ X,
          const float* __restrict__ W,
          _Float16* __restrict__ P)     // [SPL][M][N] fp16 partials
{
    __shared__ __align__(16) _Float16 LA[2][BM * BK];   // 2 x 8 KB fp16
    __shared__ __align__(16) _Float16 LB[2][BN * BK];   // 2 x 4 KB fp16

    const int tid = (int)threadIdx.x;
    const int l   = tid & 63;
    const int wv  = tid >> 6;           // 4 waves: 2(M) x 2(N), wave tile 64x32
    const int lc  = l & 15;
    const int lr  = l >> 4;
    const int wm  = (wv & 1) * 64;
    const int wn  = (wv >> 1) * 32;

    // grid 1024 = xcd(8) x [mb(2) x sp(8) x nbl(8)]; per XCD 512 W rows HBM-once.
    const int bid = (int)blockIdx.x;
    const int xcd = bid & 7;
    const int i   = bid >> 3;           // 0..127
    const int mb  = i & 1;
    const int sp  = (i >> 1) & 7;
    const int nbl = i >> 4;             // 0..7
    const int bm  = mb * BM;
    const int bn  = (xcd * 8 + nbl) * BN;
    const int kb  = sp * KSPL;

    // ---- staging maps (fp32 global -> regs; coalesced 1KB/inst) ----
    const int arow = wv * 32 + (l >> 3);             // A: 4 insts (+8 rows)
    const int wrow = wv * 16 + (l >> 3);             // W: 2 insts (+8 rows)
    const int scol = (l & 7) * 4;
    const float* ax0 = X + (size_t)(bm + arow)      * K + kb + scol;
    const float* ax1 = X + (size_t)(bm + arow + 8)  * K + kb + scol;
    const float* ax2 = X + (size_t)(bm + arow + 16) * K + kb + scol;
    const float* ax3 = X + (size_t)(bm + arow + 24) * K + kb + scol;
    const float* wx0 = W + (size_t)(bn + wrow)      * K + kb + scol;
    const float* wx1 = W + (size_t)(bn + wrow + 8)  * K + kb + scol;
    // LDS half-index write bases
    const int awr = arow * BK + (l & 7) * 4;
    const int wwr = wrow * BK + (l & 7) * 4;

    // named register slots (rule 20): 1 tile = 6 float4
    float4 sa0, sa1, sa2, sa3, sw0, sw1;

#define GLOAD(t) do { const size_t o = (size_t)(t) * BK;                \
        sa0 = *(const float4*)(ax0 + o); sa1 = *(const float4*)(ax1 + o); \
        sa2 = *(const float4*)(ax2 + o); sa3 = *(const float4*)(ax3 + o); \
        sw0 = *(const float4*)(wx0 + o); sw1 = *(const float4*)(wx1 + o); } while (0)
#define CVTW(bf) do {                                                   \
        *(half4*)(&LA[bf][awr])         = cvt4(sa0);                    \
        *(half4*)(&LA[bf][awr + 8*BK])  = cvt4(sa1);                    \
        *(half4*)(&LA[bf][awr + 16*BK]) = cvt4(sa2);                    \
        *(half4*)(&LA[bf][awr + 24*BK]) = cvt4(sa3);                    \
        *(half4*)(&LB[bf][wwr])         = cvt4(sw0);                    \
        *(half4*)(&LB[bf][wwr + 8*BK])  = cvt4(sw1); } while (0)

    f32x4 acc[4][2];
    #pragma unroll
    for (int a = 0; a < 4; ++a)
        #pragma unroll
        for (int b = 0; b < 2; ++b)
            acc[a][b] = (f32x4){0.f, 0.f, 0.f, 0.f};

    // frags: direct half8 at [row][lr*8] (16B contiguous, m97 style)
#define COMPUTE(bf) do {                                                \
        half8 af[4], wf[2];                                             \
        _Pragma("unroll")                                               \
        for (int ar = 0; ar < 4; ++ar)                                  \
            af[ar] = *(const half8*)(&LA[bf][(wm + ar * 16 + lc) * BK + lr * 8]); \
        _Pragma("unroll")                                               \
        for (int br = 0; br < 2; ++br)                                  \
            wf[br] = *(const half8*)(&LB[bf][(wn + br * 16 + lc) * BK + lr * 8]); \
        _Pragma("unroll")                                               \
        for (int ar = 0; ar < 4; ++ar)                                  \
            _Pragma("unroll")                                           \
            for (int br = 0; br < 2; ++br)                              \
                acc[ar][br] = __builtin_amdgcn_mfma_f32_16x16x32_f16(   \
                    af[ar], wf[br], acc[ar][br], 0, 0, 0); } while (0)

    // prologue: tile 0 -> buf 0
    GLOAD(0);
    asm volatile("s_waitcnt vmcnt(0)" ::: "memory");
    CVTW(0);
    asm volatile("s_waitcnt lgkmcnt(0)" ::: "memory");
    __builtin_amdgcn_s_barrier();

    for (int t = 0; t < NT; ++t) {
        if (t + 1 < NT) {
            GLOAD(t + 1);                       // issue early; lat hidden by COMPUTE+TLP
            __builtin_amdgcn_sched_barrier(0);
        }
        COMPUTE(t & 1);
        if (t + 1 < NT) {
            asm volatile("s_waitcnt vmcnt(0)" ::: "memory");   // only our 6 outstanding
            __builtin_amdgcn_sched_barrier(0);
            CVTW((t + 1) & 1);
            asm volatile("s_waitcnt lgkmcnt(0)" ::: "memory");
            __builtin_amdgcn_s_barrier();       // ONE barrier per phase
        }
    }
#undef GLOAD
#undef CVTW
#undef COMPUTE

    // fp16 partial stores. C/D: col = lane&15, row = (lane>>4)*4 + reg [m89/m91]
    _Float16* Pb = P + (size_t)sp * M * N;
    const int orow = bm + wm + lr * 4;
    const int ocol = bn + wn + lc;
    #pragma unroll
    for (int ar = 0; ar < 4; ++ar)
        #pragma unroll
        for (int br = 0; br < 2; ++br)
            #pragma unroll
            for (int r = 0; r < 4; ++r)
                Pb[(size_t)(orow + ar * 16 + r) * N + ocol + br * 16]
                    = (_Float16)acc[ar][br][r];
}

// O = fp32( fp16( fp16( (sum of SPL fp16 partials) * scale[n] ) + bias[n] ) )
// XCD-swizzled: block bid&7 == xcd handles cols [xcd*512, xcd*512+512) -> partial
// reads hit that XCD's own L2 (gemm wrote them there). If the bid->XCD round-robin
// assumption fails, this degrades to v18 finalize performance (correctness unaffected).
__global__ __launch_bounds__(256)
void finalize(const _Float16* __restrict__ P,
              const float* __restrict__ S,
              const float* __restrict__ Bi,
              float* __restrict__ O)
{
    const int bid = (int)blockIdx.x;
    const int xcd = bid & 7;
    const int j   = bid >> 3;                       // 0..63
    const int e   = (j * 256 + (int)threadIdx.x) * 8;   // within-xcd elem index
    const int row = e >> 9;                         // /512
    const int col = xcd * 512 + (e & 511);
    const size_t i = (size_t)row * N + col;
    float acc[8] = {0.f, 0.f, 0.f, 0.f, 0.f, 0.f, 0.f, 0.f};
    #pragma unroll
    for (int s = 0; s < SPL; ++s) {
        half8 u = *(const half8*)(P + (size_t)s * M * N + i);
        #pragma unroll
        for (int ee = 0; ee < 8; ++ee) acc[ee] += (float)u[ee];
    }
    float4 sc0 = *(const float4*)(S + col);
    float4 sc1 = *(const float4*)(S + col + 4);
    float4 bb0 = *(const float4*)(Bi + col);
    float4 bb1 = *(const float4*)(Bi + col + 4);
    float sc[8] = {sc0.x, sc0.y, sc0.z, sc0.w, sc1.x, sc1.y, sc1.z, sc1.w};
    float bb[8] = {bb0.x, bb0.y, bb0.z, bb0.w, bb1.x, bb1.y, bb1.z, bb1.w};
    float out[8];
    #pragma unroll
    for (int ee = 0; ee < 8; ++ee)
        out[ee] = (float)(_Float16)((float)(_Float16)(acc[ee] * sc[ee]) + bb[ee]);
    *(float4*)(O + i)     = (float4){out[0], out[1], out[2], out[3]};
    *(float4*)(O + i + 4) = (float4){out[4], out[5], out[6], out[7]};
}

// correctness fallback if d_ws is too small
__global__ __launch_bounds__(256)
void fp6lin_small(const float* __restrict__ X, const float* __restrict__ W,
                  const float* __restrict__ S, const float* __restrict__ Bi,
                  float* __restrict__ O)
{
    const int n = (int)blockIdx.x;
    const int m = (int)threadIdx.x;
    float s = 0.f;
    for (int k = 0; k < K; ++k)
        s += (float)(_Float16)X[(size_t)m * K + k] * (float)(_Float16)W[(size_t)n * K + k];
    O[(size_t)m * N + n] = (float)(_Float16)((float)(_Float16)(s * S[n]) + Bi[n]);
}

extern "C" void kernel_launch(void* const* d_in, const int* in_sizes, int n_in,
                              void* d_out, int out_size, void* d_ws, size_t ws_size,
                              hipStream_t stream) {
    const float* x  = (const float*)d_in[0];
    const float* w  = (const float*)d_in[1];
    const float* s  = (const float*)d_in[2];
    const float* bi = (const float*)d_in[3];
    float* o = (float*)d_out;

    const size_t pbytes = (size_t)SPL * M * N * 2;   // 16 MB fp16 partials
    _Float16* P = (_Float16*)d_ws;

    if (ws_size >= pbytes) {
        gemm<<<dim3(1024), dim3(256), 0, stream>>>(x, w, P);
        finalize<<<dim3(512), dim3(256), 0, stream>>>(P, s, bi, o);
    } else {
        fp6lin_small<<<dim3(N), dim3(M), 0, stream>>>(x, w, s, bi, o);
    }
}

// Round 30
// 30.680 us; speedup vs baseline: 1.1354x; 1.0086x over previous
//
#include <hip/hip_runtime.h>
#include <hip/hip_fp16.h>

// out[m][n] = fp16( fp16( (sum_k x[m][k]*w6[n][k]) * scale[n] ) + bias[n] ), stored fp32
// FINAL (v23, measured best 30.5us): tile 128x64, BK=32, 4 waves (wave-tile 64x32,
// acc=32 VGPR), grid 1024 -> 4 blocks/CU. Reg-staged fp32->fp16 cvt (exact for
// fp16-exact inputs), linear fp16 LDS, asm-fenced waits, ONE raw barrier/phase,
// XCD-mapped blocks (per-XCD W panels HBM-read once), SPL=8 streamed fp16 partials
// + vectorized finalize with the reference's double rounding.
// Session conclusion: every single-variable perturbation (BK=64, DMA staging, deeper
// prefetch, padding, barrier-free, fused finalize, cooperative) regressed; the ~30us
// plateau is the barrier-phased HIP-source schedule class ceiling (~2.6 TB/s duty-
// cycled vs 6.9 TB/s raw), not a hardware roofline.

typedef __attribute__((ext_vector_type(8))) _Float16 half8;
typedef __attribute__((ext_vector_type(4))) _Float16 half4;
typedef __attribute__((ext_vector_type(2))) __fp16 fp16x2;   // cvt_pkrtz return type
typedef __attribute__((ext_vector_type(4))) float f32x4;

constexpr int K = 4096, N = 4096, M = 256;
constexpr int BM = 128, BN = 64, BK = 32;
constexpr int SPL = 8;
constexpr int KSPL = K / SPL;     // 512
constexpr int NT = KSPL / BK;     // 16 phases

__device__ __forceinline__ half4 cvt4(float4 f) {   // exact: fp16-exact data
    fp16x2 p0 = __builtin_amdgcn_cvt_pkrtz(f.x, f.y);
    fp16x2 p1 = __builtin_amdgcn_cvt_pkrtz(f.z, f.w);
    half4 h;
    h[0]=(_Float16)p0[0]; h[1]=(_Float16)p0[1];
    h[2]=(_Float16)p1[0]; h[3]=(_Float16)p1[1];
    return h;
}

__global__ __launch_bounds__(256, 4)
void gemm(const float* __restrict__ X,
          const float* __restrict__ W,
          _Float16* __restrict__ P)     // [SPL][M][N] fp16 partials
{
    __shared__ __align__(16) _Float16 LA[2][BM * BK];   // 2 x 8 KB fp16
    __shared__ __align__(16) _Float16 LB[2][BN * BK];   // 2 x 4 KB fp16

    const int tid = (int)threadIdx.x;
    const int l   = tid & 63;
    const int wv  = tid >> 6;           // 4 waves: 2(M) x 2(N), wave tile 64x32
    const int lc  = l & 15;
    const int lr  = l >> 4;
    const int wm  = (wv & 1) * 64;
    const int wn  = (wv >> 1) * 32;

    // grid 1024 = xcd(8) x [mb(2) x sp(8) x nbl(8)]. Per XCD: 8 N-panels x 64 rows
    // = 512 W rows (8 MB) HBM-read once; the 2 mb-sharers of each panel co-resident.
    const int bid = (int)blockIdx.x;
    const int xcd = bid & 7;
    const int i   = bid >> 3;           // 0..127
    const int mb  = i & 1;
    const int sp  = (i >> 1) & 7;
    const int nbl = i >> 4;             // 0..7
    const int bm  = mb * BM;
    const int bn  = (xcd * 8 + nbl) * BN;
    const int kb  = sp * KSPL;

    // ---- staging maps (fp32 global -> regs; coalesced 1KB/inst) ----
    const int arow = wv * 32 + (l >> 3);             // A: 4 insts (+8 rows)
    const int wrow = wv * 16 + (l >> 3);             // W: 2 insts (+8 rows)
    const int scol = (l & 7) * 4;
    const float* ax0 = X + (size_t)(bm + arow)      * K + kb + scol;
    const float* ax1 = X + (size_t)(bm + arow + 8)  * K + kb + scol;
    const float* ax2 = X + (size_t)(bm + arow + 16) * K + kb + scol;
    const float* ax3 = X + (size_t)(bm + arow + 24) * K + kb + scol;
    const float* wx0 = W + (size_t)(bn + wrow)      * K + kb + scol;
    const float* wx1 = W + (size_t)(bn + wrow + 8)  * K + kb + scol;
    // LDS half-index write bases
    const int awr = arow * BK + (l & 7) * 4;
    const int wwr = wrow * BK + (l & 7) * 4;

    // named register slots (rule 20): 1 tile = 6 float4
    float4 sa0, sa1, sa2, sa3, sw0, sw1;

#define GLOAD(t) do { const size_t o = (size_t)(t) * BK;                \
        sa0 = *(const float4*)(ax0 + o); sa1 = *(const float4*)(ax1 + o); \
        sa2 = *(const float4*)(ax2 + o); sa3 = *(const float4*)(ax3 + o); \
        sw0 = *(const float4*)(wx0 + o); sw1 = *(const float4*)(wx1 + o); } while (0)
#define CVTW(bf) do {                                                   \
        *(half4*)(&LA[bf][awr])         = cvt4(sa0);                    \
        *(half4*)(&LA[bf][awr + 8*BK])  = cvt4(sa1);                    \
        *(half4*)(&LA[bf][awr + 16*BK]) = cvt4(sa2);                    \
        *(half4*)(&LA[bf][awr + 24*BK]) = cvt4(sa3);                    \
        *(half4*)(&LB[bf][wwr])         = cvt4(sw0);                    \
        *(half4*)(&LB[bf][wwr + 8*BK])  = cvt4(sw1); } while (0)

    f32x4 acc[4][2];
    #pragma unroll
    for (int a = 0; a < 4; ++a)
        #pragma unroll
        for (int b = 0; b < 2; ++b)
            acc[a][b] = (f32x4){0.f, 0.f, 0.f, 0.f};

    // frags: direct half8 at [row][lr*8] (16B contiguous, m97 style)
#define COMPUTE(bf) do {                                                \
        half8 af[4], wf[2];                                             \
        _Pragma("unroll")                                               \
        for (int ar = 0; ar < 4; ++ar)                                  \
            af[ar] = *(const half8*)(&LA[bf][(wm + ar * 16 + lc) * BK + lr * 8]); \
        _Pragma("unroll")                                               \
        for (int br = 0; br < 2; ++br)                                  \
            wf[br] = *(const half8*)(&LB[bf][(wn + br * 16 + lc) * BK + lr * 8]); \
        _Pragma("unroll")                                               \
        for (int ar = 0; ar < 4; ++ar)                                  \
            _Pragma("unroll")                                           \
            for (int br = 0; br < 2; ++br)                              \
                acc[ar][br] = __builtin_amdgcn_mfma_f32_16x16x32_f16(   \
                    af[ar], wf[br], acc[ar][br], 0, 0, 0); } while (0)

    // prologue: tile 0 -> buf 0
    GLOAD(0);
    asm volatile("s_waitcnt vmcnt(0)" ::: "memory");
    CVTW(0);
    asm volatile("s_waitcnt lgkmcnt(0)" ::: "memory");
    __builtin_amdgcn_s_barrier();

    for (int t = 0; t < NT; ++t) {
        if (t + 1 < NT) {
            GLOAD(t + 1);                       // issue early; lat hidden by COMPUTE+TLP
            __builtin_amdgcn_sched_barrier(0);
        }
        COMPUTE(t & 1);
        if (t + 1 < NT) {
            asm volatile("s_waitcnt vmcnt(0)" ::: "memory");   // only our 6 outstanding
            __builtin_amdgcn_sched_barrier(0);
            CVTW((t + 1) & 1);
            asm volatile("s_waitcnt lgkmcnt(0)" ::: "memory");
            __builtin_amdgcn_s_barrier();       // ONE barrier per phase
        }
    }
#undef GLOAD
#undef CVTW
#undef COMPUTE

    // fp16 partial stores. C/D: col = lane&15, row = (lane>>4)*4 + reg [m89/m91]
    _Float16* Pb = P + (size_t)sp * M * N;
    const int orow = bm + wm + lr * 4;
    const int ocol = bn + wn + lc;
    #pragma unroll
    for (int ar = 0; ar < 4; ++ar)
        #pragma unroll
        for (int br = 0; br < 2; ++br)
            #pragma unroll
            for (int r = 0; r < 4; ++r)
                Pb[(size_t)(orow + ar * 16 + r) * N + ocol + br * 16]
                    = (_Float16)acc[ar][br][r];
}

// O = fp32( fp16( fp16( (sum of SPL fp16 partials) * scale[n] ) + bias[n] ) )
__global__ __launch_bounds__(256)
void finalize(const _Float16* __restrict__ P,
              const float* __restrict__ S,
              const float* __restrict__ Bi,
              float* __restrict__ O)
{
    const size_t i = ((size_t)blockIdx.x * 256 + threadIdx.x) * 8;
    const int n = (int)(i & (N - 1));
    float acc[8] = {0.f, 0.f, 0.f, 0.f, 0.f, 0.f, 0.f, 0.f};
    #pragma unroll
    for (int s = 0; s < SPL; ++s) {
        half8 u = *(const half8*)(P + (size_t)s * M * N + i);
        #pragma unroll
        for (int e = 0; e < 8; ++e) acc[e] += (float)u[e];
    }
    float4 sc0 = *(const float4*)(S + n);
    float4 sc1 = *(const float4*)(S + n + 4);
    float4 bb0 = *(const float4*)(Bi + n);
    float4 bb1 = *(const float4*)(Bi + n + 4);
    float sc[8] = {sc0.x, sc0.y, sc0.z, sc0.w, sc1.x, sc1.y, sc1.z, sc1.w};
    float bb[8] = {bb0.x, bb0.y, bb0.z, bb0.w, bb1.x, bb1.y, bb1.z, bb1.w};
    float out[8];
    #pragma unroll
    for (int e = 0; e < 8; ++e)
        out[e] = (float)(_Float16)((float)(_Float16)(acc[e] * sc[e]) + bb[e]);
    *(float4*)(O + i)     = (float4){out[0], out[1], out[2], out[3]};
    *(float4*)(O + i + 4) = (float4){out[4], out[5], out[6], out[7]};
}

// correctness fallback if d_ws is too small
__global__ __launch_bounds__(256)
void fp6lin_small(const float* __restrict__ X, const float* __restrict__ W,
                  const float* __restrict__ S, const float* __restrict__ Bi,
                  float* __restrict__ O)
{
    const int n = (int)blockIdx.x;
    const int m = (int)threadIdx.x;
    float s = 0.f;
    for (int k = 0; k < K; ++k)
        s += (float)(_Float16)X[(size_t)m * K + k] * (float)(_Float16)W[(size_t)n * K + k];
    O[(size_t)m * N + n] = (float)(_Float16)((float)(_Float16)(s * S[n]) + Bi[n]);
}

extern "C" void kernel_launch(void* const* d_in, const int* in_sizes, int n_in,
                              void* d_out, int out_size, void* d_ws, size_t ws_size,
                              hipStream_t stream) {
    const float* x  = (const float*)d_in[0];
    const float* w  = (const float*)d_in[1];
    const float* s  = (const float*)d_in[2];
    const float* bi = (const float*)d_in[3];
    float* o = (float*)d_out;

    const size_t pbytes = (size_t)SPL * M * N * 2;   // 16 MB fp16 partials
    _Float16* P = (_Float16*)d_ws;

    if (ws_size >= pbytes) {
        gemm<<<dim3(1024), dim3(256), 0, stream>>>(x, w, P);
        finalize<<<dim3(M * N / 8 / 256), dim3(256), 0, stream>>>(P, s, bi, o);
    } else {
        fp6lin_small<<<dim3(N), dim3(M), 0, stream>>>(x, w, s, bi, o);
    }
}